// Round 1
// baseline (369.847 us; speedup 1.0000x reference)
//
#include <hip/hip_runtime.h>
#include <stdint.h>

// ---------------- Problem constants ----------------
#define T_TOK 8192
#define DDIM  1024
#define NEXP  16
#define MAXTILES 144   // worst case: 16384/128 + 16

typedef unsigned short u16;
typedef __attribute__((ext_vector_type(8))) short v8s;   // 8 x bf16 (4 VGPRs)
typedef __attribute__((ext_vector_type(4))) float v4f;   // 4 x f32 acc

// fp32 -> bf16 round-to-nearest-even (no NaN handling needed; data is finite)
__device__ __forceinline__ u16 f2bf(float f) {
  union { float f; unsigned u; } v; v.f = f;
  unsigned r = v.u + 0x7fffu + ((v.u >> 16) & 1u);
  return (u16)(r >> 16);
}

// async global->LDS, 16B per lane. LDS dest is wave-uniform base + lane*16.
__device__ __forceinline__ void gload_lds16(const u16* gsrc, u16* ldst) {
  typedef __attribute__((address_space(1))) const void GV;
  typedef __attribute__((address_space(3))) void LV;
  __builtin_amdgcn_global_load_lds((GV*)(uintptr_t)gsrc, (LV*)(uintptr_t)ldst, 16, 0, 0);
}

// ---------------- fp32 -> bf16 conversions ----------------
__global__ __launch_bounds__(256) void k_cvt4(const float4* __restrict__ in,
                                              ushort4* __restrict__ out, int n4) {
  int i = blockIdx.x * 256 + threadIdx.x;
  if (i >= n4) return;
  float4 v = in[i];
  ushort4 o; o.x = f2bf(v.x); o.y = f2bf(v.y); o.z = f2bf(v.z); o.w = f2bf(v.w);
  out[i] = o;
}

// Wc[h,d] = sw[h,d] + sw[1024+h,d]  (chunk stride = 1M floats = n4 float4s)
__global__ __launch_bounds__(256) void k_cvt_shared(const float4* __restrict__ sw,
                                                    ushort4* __restrict__ out, int n4) {
  int i = blockIdx.x * 256 + threadIdx.x;
  if (i >= n4) return;
  float4 a = sw[i];
  float4 b = sw[i + n4];
  ushort4 o;
  o.x = f2bf(a.x + b.x); o.y = f2bf(a.y + b.y);
  o.z = f2bf(a.z + b.z); o.w = f2bf(a.w + b.w);
  out[i] = o;
}

// ---------------- Router: logits, softmax, top-2, counts/pi ----------------
// 256 threads = 4 waves; each wave handles 8 tokens; grid = 256 blocks (8192 tokens)
__global__ __launch_bounds__(256) void k_router(const float* __restrict__ x,
                                                const float* __restrict__ rw,
                                                int* __restrict__ topkI,
                                                float* __restrict__ topkW,
                                                int* __restrict__ counts,
                                                float* __restrict__ piSum) {
  __shared__ float lds_pi[NEXP];
  __shared__ int   lds_cnt[NEXP];
  int tid = threadIdx.x;
  if (tid < NEXP) { lds_pi[tid] = 0.f; lds_cnt[tid] = 0; }
  __syncthreads();
  int lane = tid & 63, wave = tid >> 6;

  for (int ti = 0; ti < 8; ++ti) {
    int t = blockIdx.x * 32 + wave * 8 + ti;
    const float* xr = x + (size_t)t * DDIM;
    float xv[16];
#pragma unroll
    for (int i = 0; i < 16; ++i) xv[i] = xr[i * 64 + lane];
    float lg[NEXP];
#pragma unroll
    for (int e = 0; e < NEXP; ++e) {
      const float* wr = rw + (size_t)e * DDIM;
      float p = 0.f;
#pragma unroll
      for (int i = 0; i < 16; ++i) p += xv[i] * wr[i * 64 + lane];
#pragma unroll
      for (int off = 32; off > 0; off >>= 1) p += __shfl_xor(p, off);
      lg[e] = p;   // full-wave butterfly: all lanes hold the sum
    }
    // softmax denom (for pi) + top-2, computed redundantly on all lanes
    float mx = lg[0];
#pragma unroll
    for (int e = 1; e < NEXP; ++e) mx = fmaxf(mx, lg[e]);
    float sum = 0.f;
#pragma unroll
    for (int e = 0; e < NEXP; ++e) sum += __expf(lg[e] - mx);
    float v0 = lg[0]; int i0 = 0;
#pragma unroll
    for (int e = 1; e < NEXP; ++e) if (lg[e] > v0) { v0 = lg[e]; i0 = e; }
    float v1 = -3.0e38f; int i1 = 0;
#pragma unroll
    for (int e = 0; e < NEXP; ++e) if (e != i0 && lg[e] > v1) { v1 = lg[e]; i1 = e; }
    float e1 = __expf(v1 - v0);
    float w0 = 1.f / (1.f + e1);
    float w1 = e1 / (1.f + e1);
    if (lane == 0) {
      topkI[2 * t] = i0; topkI[2 * t + 1] = i1;
      topkW[2 * t] = w0; topkW[2 * t + 1] = w1;
      atomicAdd(&lds_cnt[i0], 1); atomicAdd(&lds_cnt[i1], 1);
    }
#pragma unroll
    for (int e = 0; e < NEXP; ++e)          // static index; one lane per expert
      if (lane == e) atomicAdd(&lds_pi[e], __expf(lg[e] - mx) / sum);
  }
  __syncthreads();
  if (tid < NEXP) {
    atomicAdd(&counts[tid], lds_cnt[tid]);
    atomicAdd(&piSum[tid], lds_pi[tid]);
  }
}

// ---------------- Finalize routing: offsets, tile list, aux loss ----------------
__global__ void k_finalize(const int* __restrict__ counts, const float* __restrict__ piSum,
                           int* __restrict__ offs, int* __restrict__ meta,
                           int* __restrict__ ntile, int* __restrict__ cursor,
                           float* __restrict__ outAux) {
  if (threadIdx.x != 0) return;
  int off = 0;
  for (int e = 0; e < NEXP; ++e) { offs[e] = off; off += counts[e]; }
  offs[NEXP] = off;
  int nt = 0;
  for (int e = 0; e < NEXP; ++e) {
    for (int rs = 0; rs < counts[e]; rs += 128) { meta[2 * nt] = e; meta[2 * nt + 1] = rs; ++nt; }
    cursor[e] = 0;
  }
  ntile[0] = nt;
  float aux = 0.f;
  for (int e = 0; e < NEXP; ++e)
    aux += (piSum[e] / (float)T_TOK) * ((float)counts[e] / (float)T_TOK);
  outAux[0] = aux;
}

// ---------------- Scatter token-expert pairs into buckets ----------------
__global__ __launch_bounds__(256) void k_scatter(const int* __restrict__ topkI,
                                                 const float* __restrict__ topkW,
                                                 const int* __restrict__ offs,
                                                 int* __restrict__ cursor,
                                                 int* __restrict__ rowTok,
                                                 float* __restrict__ rowW) {
  __shared__ int lcnt[NEXP], lbase[NEXP];
  int tid = threadIdx.x;
  if (tid < NEXP) lcnt[tid] = 0;
  __syncthreads();
  int p = blockIdx.x * 256 + tid;             // pair id, 0..16383
  int e = topkI[p];
  int myLocal = atomicAdd(&lcnt[e], 1);
  __syncthreads();
  if (tid < NEXP) lbase[tid] = atomicAdd(&cursor[tid], lcnt[tid]);
  __syncthreads();
  int dst = offs[e] + lbase[e] + myLocal;
  rowTok[dst] = p >> 1;
  rowW[dst] = topkW[p];
}

// ---------------- Grouped bf16 MFMA GEMM (m97 structure) ----------------
// BM=BN=128, BK=32; 4 waves, each wave 64x64 = 4x4 frags of 16x16x32.
// mode 0: shared expert (slot 16 weights), identity rows, plain store.
// mode 1: routed experts, gathered rows, atomicAdd(w * acc).
__global__ __launch_bounds__(256) void k_gemm(const u16* __restrict__ xb,
                                              const u16* __restrict__ wb,
                                              const int* __restrict__ meta,
                                              const int* __restrict__ ntile,
                                              const int* __restrict__ offs,
                                              const int* __restrict__ rowTok,
                                              const float* __restrict__ rowW,
                                              float* __restrict__ out, int mode) {
  __shared__ u16 As[128 * 32];
  __shared__ u16 Bs[128 * 32];
  int tid = threadIdx.x;
  int lane = tid & 63, wave = tid >> 6;
  int tileN = blockIdx.y;

  int e, rowStart, offBase = 0, cnt = 128;
  if (mode == 0) {
    e = NEXP; rowStart = blockIdx.x * 128;
  } else {
    int ti = blockIdx.x;
    if (ti >= ntile[0]) return;
    e = meta[2 * ti]; rowStart = meta[2 * ti + 1];
    offBase = offs[e]; cnt = offs[e + 1] - offBase;
  }

  // staging coords: thread tid covers 16B chunk (row = tid/4, chunk = tid%4)
  int sRow = tid >> 2;
  int sChunk = tid & 3;
  int tok0, tok1;
  if (mode == 0) {
    tok0 = rowStart + sRow; tok1 = rowStart + 64 + sRow;
  } else {
    int r0 = min(rowStart + sRow, cnt - 1);
    int r1 = min(rowStart + 64 + sRow, cnt - 1);
    tok0 = rowTok[offBase + r0]; tok1 = rowTok[offBase + r1];
  }
  const u16* wbase = wb + (size_t)e * (DDIM * DDIM) + (size_t)(tileN * 128) * DDIM;
  const u16* aSrc0 = xb + (size_t)tok0 * DDIM + sChunk * 8;
  const u16* aSrc1 = xb + (size_t)tok1 * DDIM + sChunk * 8;
  const u16* bSrc0 = wbase + (size_t)sRow * DDIM + sChunk * 8;
  const u16* bSrc1 = wbase + (size_t)(64 + sRow) * DDIM + sChunk * 8;
  u16* aDst0 = As + wave * 512;          // wave-uniform LDS chunk bases
  u16* aDst1 = As + 2048 + wave * 512;
  u16* bDst0 = Bs + wave * 512;
  u16* bDst1 = Bs + 2048 + wave * 512;

  v4f acc[4][4];
#pragma unroll
  for (int m = 0; m < 4; ++m)
#pragma unroll
    for (int n = 0; n < 4; ++n) acc[m][n] = (v4f)0.f;

  int wm = (wave >> 1) * 64, wn = (wave & 1) * 64;
  int rsel = lane & 15;
  int kb = (lane >> 4) * 8;

  for (int kk = 0; kk < DDIM / 32; ++kk) {
    int k0 = kk * 32;
    __syncthreads();                      // previous iter's reads done
    gload_lds16(aSrc0 + k0, aDst0);
    gload_lds16(aSrc1 + k0, aDst1);
    gload_lds16(bSrc0 + k0, bDst0);
    gload_lds16(bSrc1 + k0, bDst1);
    __syncthreads();                      // drains vmcnt -> LDS tiles ready

    v8s af[4], bfr[4];
#pragma unroll
    for (int m = 0; m < 4; ++m)
      af[m] = *(const v8s*)(As + (wm + m * 16 + rsel) * 32 + kb);
#pragma unroll
    for (int n = 0; n < 4; ++n)
      bfr[n] = *(const v8s*)(Bs + (wn + n * 16 + rsel) * 32 + kb);
#pragma unroll
    for (int m = 0; m < 4; ++m)
#pragma unroll
      for (int n = 0; n < 4; ++n)
        acc[m][n] = __builtin_amdgcn_mfma_f32_16x16x32_bf16(af[m], bfr[n], acc[m][n], 0, 0, 0);
  }

  // epilogue: C/D layout col=lane&15, row=(lane>>4)*4+j  [m89-verified]
  int colBase = tileN * 128 + wn + (lane & 15);
  if (mode == 0) {
#pragma unroll
    for (int m = 0; m < 4; ++m) {
      int rBase = rowStart + wm + m * 16 + (lane >> 4) * 4;
#pragma unroll
      for (int n = 0; n < 4; ++n) {
        v4f a = acc[m][n];
        int col = colBase + n * 16;
#pragma unroll
        for (int j = 0; j < 4; ++j)
          out[(size_t)(rBase + j) * DDIM + col] = a[j];
      }
    }
  } else {
#pragma unroll
    for (int m = 0; m < 4; ++m) {
      int rloc = rowStart + wm + m * 16 + (lane >> 4) * 4;
#pragma unroll
      for (int j = 0; j < 4; ++j) {
        int r = rloc + j;
        if (r < cnt) {
          int idx = offBase + r;
          int t = rowTok[idx];
          float w = rowW[idx];
          float* orow = out + (size_t)t * DDIM;
#pragma unroll
          for (int n = 0; n < 4; ++n)
            atomicAdd(orow + colBase + n * 16, w * acc[m][n][j]);
        }
      }
    }
  }
}

// ---------------- launch ----------------
extern "C" void kernel_launch(void* const* d_in, const int* in_sizes, int n_in,
                              void* d_out, int out_size, void* d_ws, size_t ws_size,
                              hipStream_t stream) {
  const float* feat = (const float*)d_in[0];  // [8192][1024]
  const float* rw   = (const float*)d_in[1];  // [16][1024]
  const float* sw   = (const float*)d_in[2];  // [2048][1024]
  const float* ew   = (const float*)d_in[3];  // [16][1024][1024]
  float* out = (float*)d_out;                 // [8192*1024] + aux at [8388608]
  char* ws = (char*)d_ws;

  // ws layout (needs ~52.7 MB)
  u16* xb = (u16*)(ws + 0);                         // 16,777,216 B
  u16* wb = (u16*)(ws + 16777216);                  // 17 x 2 MB = 35,651,584 B
  char* smallBase = ws + 52428800;
  int*   counts = (int*)(smallBase + 0);
  float* piSum  = (float*)(smallBase + 64);
  int*   cursor = (int*)(smallBase + 128);
  int*   ntile  = (int*)(smallBase + 192);
  int*   topkI  = (int*)(ws + 52429056);
  float* topkW  = (float*)(ws + 52494592);
  int*   offs   = (int*)(ws + 52560128);
  int*   rowTok = (int*)(ws + 52560256);
  float* rowW   = (float*)(ws + 52625792);
  int*   meta   = (int*)(ws + 52691328);

  hipMemsetAsync(smallBase, 0, 256, stream);

  k_cvt4<<<8192, 256, 0, stream>>>((const float4*)feat, (ushort4*)xb, 2097152);
  k_cvt4<<<16384, 256, 0, stream>>>((const float4*)ew, (ushort4*)wb, 4194304);
  k_cvt_shared<<<1024, 256, 0, stream>>>((const float4*)sw,
                                         (ushort4*)(wb + (size_t)NEXP * DDIM * DDIM), 262144);

  k_router<<<256, 256, 0, stream>>>(feat, rw, topkI, topkW, counts, piSum);
  k_finalize<<<1, 64, 0, stream>>>(counts, piSum, offs, meta, ntile, cursor, out + 8388608);
  k_scatter<<<64, 256, 0, stream>>>(topkI, topkW, offs, cursor, rowTok, rowW);

  dim3 gShared(64, 8), gExpert(MAXTILES, 8);
  k_gemm<<<gShared, 256, 0, stream>>>(xb, wb, meta, ntile, offs, rowTok, rowW, out, 0);
  k_gemm<<<gExpert, 256, 0, stream>>>(xb, wb, meta, ntile, offs, rowTok, rowW, out, 1);
}